// Round 2
// baseline (220.654 us; speedup 1.0000x reference)
//
#include <hip/hip_runtime.h>
#include <hip/hip_bf16.h>

// B=32768, D=1024, U=1024, R=4, H=16, ND=11
// out = relu(x@kernel + bias_tot + (dom @ Beff)), dom from tiny collapsed attention.

typedef float f32x4 __attribute__((ext_vector_type(4)));
typedef short s16x8 __attribute__((ext_vector_type(8)));
typedef unsigned int u32x4 __attribute__((ext_vector_type(4)));

// ws layout (bytes)
#define WS_DOM    0u         // 32768*4 f32           = 524288
#define WS_BEFF   524288u    // 4*1024 f32            = 16384
#define WS_BIAS   540672u    // 1024 f32              = 4096
#define WS_G      544768u    // 16 f32
#define WS_M      545024u    // 16 f32
#define WS_ACATT  545280u    // 64*1024 bf16          = 131072
#define WS_KB     679936u    // 1024*1024 bf16        = 2097152 (ends 2777088)

__device__ __forceinline__ unsigned short f2bf(float f) {
  unsigned int u = __builtin_bit_cast(unsigned int, f);
  u += 0x7fffu + ((u >> 16) & 1u);   // round-to-nearest-even
  return (unsigned short)(u >> 16);
}
__device__ __forceinline__ unsigned int f2bf2(float a, float b) {
  return (unsigned int)f2bf(a) | ((unsigned int)f2bf(b) << 16);
}

__device__ __forceinline__ void gload_lds16(const void* g, void* l) {
  __builtin_amdgcn_global_load_lds((const __attribute__((address_space(1))) void*)g,
                                   (__attribute__((address_space(3))) void*)l, 16, 0, 0);
}

// ---------------- prep1: w, G, M, bias_tot, Beff ----------------
__global__ void prep1(const float* __restrict__ factor, const float* __restrict__ WQ,
                      const float* __restrict__ WK, const float* __restrict__ WV,
                      const float* __restrict__ linear, const float* __restrict__ bias,
                      const float* __restrict__ domain_bias, const float* __restrict__ b_kernel,
                      const int* __restrict__ dom_ind, float* __restrict__ ws_f) {
  __shared__ float wsm[10];
  const int t = threadIdx.x;
  float* G    = ws_f + (WS_G >> 2);
  float* M    = ws_f + (WS_M >> 2);
  float* beff = ws_f + (WS_BEFF >> 2);
  float* btot = ws_f + (WS_BIAS >> 2);
  if (t == 0) {
    float f[11], mx = -1e30f;
    for (int i = 0; i < 11; i++) { f[i] = factor[i]; mx = fmaxf(mx, f[i]); }
    float s = 0.f;
    for (int i = 0; i < 11; i++) { f[i] = expf(f[i] - mx); s += f[i]; }
    float inv = 1.0f / s;
    for (int i = 0; i < 10; i++) wsm[i] = f[i + 1] * inv;
  }
  if (t < 16) {
    int r = t >> 2, c = t & 3;
    float g = 0.f, m = 0.f;
    for (int h = 0; h < 16; h++) {
      g += WQ[r * 16 + h] * WK[c * 16 + h];
      m += WV[r * 16 + h] * linear[h * 4 + c];
    }
    G[t] = 0.25f * g;   // scale = 1/sqrt(H) = 0.25
    M[t] = m;
  }
  __syncthreads();
  const int idx = dom_ind[0];
  for (int u = t; u < 1024; u += 256) btot[u] = bias[u] + domain_bias[idx * 1024 + u];
  for (int i = t; i < 4096; i += 256) {
    int r = i >> 10, u = i & 1023;
    float s = 0.f;
    for (int n = 0; n < 10; n++) s += wsm[n] * b_kernel[(1 + n) * 4096 + r * 1024 + u];
    beff[i] = s;
  }
}

// ---------------- prep2: Acatt[c][d] bf16, c=n*4+r (transposed, zero-padded to 64) ----------------
__global__ void prep2(const float* __restrict__ a_kernel, unsigned short* __restrict__ acatt) {
  const int i = blockIdx.x * 256 + threadIdx.x;  // 65536
  const int c = i >> 10, d = i & 1023;
  float v = 0.0f;
  if (c < 40) v = a_kernel[(1 + (c >> 2)) * 4096 + d * 4 + (c & 3)];
  acatt[i] = f2bf(v);
}

// ---------------- transK: kb[n][k] = bf16(kernel[k][n]) ----------------
__global__ void transK(const float* __restrict__ kern, unsigned short* __restrict__ kb) {
  __shared__ float tile[32][33];
  const int t = threadIdx.x;
  const int kt = blockIdx.x >> 5, nt = blockIdx.x & 31;
  const int k0 = kt << 5, n0 = nt << 5;
  const int row = t >> 5, col = t & 31;
#pragma unroll
  for (int i = 0; i < 4; i++)
    tile[row + i * 8][col] = kern[(k0 + row + i * 8) * 1024 + n0 + col];
  __syncthreads();
  const int nrow = t >> 3, kq = t & 7;
  uint2 pv;
  pv.x = f2bf2(tile[kq * 4 + 0][nrow], tile[kq * 4 + 1][nrow]);
  pv.y = f2bf2(tile[kq * 4 + 2][nrow], tile[kq * 4 + 3][nrow]);
  *reinterpret_cast<uint2*>(&kb[(n0 + nrow) * 1024 + k0 + kq * 4]) = pv;
}

// ---------------- stageA: dA = x@Acat (MFMA) + collapsed attention -> dom[B][4] ----------------
__launch_bounds__(256, 2)
__global__ void stageA(const float* __restrict__ x, const unsigned short* __restrict__ acatt,
                       const float* __restrict__ ws_f, float* __restrict__ dom) {
  __shared__ unsigned short As[64 * 64];   // [row][chunk^swz][8] bf16
  __shared__ unsigned short Bs[64 * 64];
  __shared__ float dAs[64][45];
  const int t = threadIdx.x;
  const int w = t >> 6, l = t & 63;
  const int rows0 = blockIdx.x << 6;
  const int lr = l & 15, kg = l >> 4;
  const f32x4 zero4 = {0.f, 0.f, 0.f, 0.f};
  f32x4 acc[3]; acc[0] = zero4; acc[1] = zero4; acc[2] = zero4;

#pragma unroll 1
  for (int kc = 0; kc < 16; kc++) {
    if (kc) __syncthreads();
    // B tile: Acatt rows (already bf16) via source-pre-swizzled global_load_lds
#pragma unroll
    for (int i = 0; i < 2; i++) {
      int segid = i * 256 + t;
      int c = segid >> 3, ks = segid & 7;
      gload_lds16(acatt + c * 1024 + (kc << 6) + ((ks ^ (c & 7)) << 3), Bs + segid * 8);
    }
    // A tile: x f32 -> bf16 reg-staged, swizzled ds_write
#pragma unroll
    for (int i = 0; i < 2; i++) {
      int segid = i * 256 + t;
      int row = segid >> 3, ks = segid & 7;
      const float* gp = x + (rows0 + row) * 1024 + (kc << 6) + (ks << 3);
      f32x4 v0 = *reinterpret_cast<const f32x4*>(gp);
      f32x4 v1 = *reinterpret_cast<const f32x4*>(gp + 4);
      u32x4 o = { f2bf2(v0[0], v0[1]), f2bf2(v0[2], v0[3]),
                  f2bf2(v1[0], v1[1]), f2bf2(v1[2], v1[3]) };
      *reinterpret_cast<u32x4*>(As + row * 64 + ((ks ^ (row & 7)) << 3)) = o;
    }
    __syncthreads();
#pragma unroll
    for (int kh = 0; kh < 2; kh++) {
      const int cp = (kh << 2) + kg;
      const int arow = (w << 4) + lr;
      s16x8 av = *reinterpret_cast<const s16x8*>(As + arow * 64 + ((cp ^ (arow & 7)) << 3));
#pragma unroll
      for (int nf = 0; nf < 3; nf++) {
        int brow = (nf << 4) + lr;
        s16x8 bv = *reinterpret_cast<const s16x8*>(Bs + brow * 64 + ((cp ^ (brow & 7)) << 3));
        acc[nf] = __builtin_amdgcn_mfma_f32_16x16x32_bf16(av, bv, acc[nf], 0, 0, 0);
      }
    }
  }
  __syncthreads();
  // scatter dA (cols 0..39) into LDS; each wave owns its 16 rows fully
#pragma unroll
  for (int nf = 0; nf < 3; nf++) {
    int col = (nf << 4) + lr;
    if (col < 40) {
#pragma unroll
      for (int j = 0; j < 4; j++)
        dAs[(w << 4) + (kg << 2) + j][col] = acc[nf][j];
    }
  }
  __syncthreads();
  if (l < 16) {
    const int row = (w << 4) + l;
    const float* Gp = ws_f + (WS_G >> 2);
    const float* Mp = ws_f + (WS_M >> 2);
    float dA[10][4];
#pragma unroll
    for (int m = 0; m < 10; m++)
#pragma unroll
      for (int r = 0; r < 4; r++) dA[m][r] = dAs[row][(m << 2) + r];
    float Gv[16], Mv[16];
#pragma unroll
    for (int i = 0; i < 16; i++) { Gv[i] = Gp[i]; Mv[i] = Mp[i]; }
    // t[m][r] = sum_s G[r][s] dA[m][s];  S[n][m] = dA[n] . t[m]
    float tm[10][4];
#pragma unroll
    for (int m = 0; m < 10; m++)
#pragma unroll
      for (int r = 0; r < 4; r++)
        tm[m][r] = Gv[(r << 2) + 0] * dA[m][0] + Gv[(r << 2) + 1] * dA[m][1]
                 + Gv[(r << 2) + 2] * dA[m][2] + Gv[(r << 2) + 3] * dA[m][3];
    float cm[10];
#pragma unroll
    for (int m = 0; m < 10; m++) cm[m] = 0.f;
#pragma unroll
    for (int n = 0; n < 10; n++) {
      float sv[10]; float mx = -1e30f;
#pragma unroll
      for (int m = 0; m < 10; m++) {
        float s = dA[n][0] * tm[m][0] + dA[n][1] * tm[m][1]
                + dA[n][2] * tm[m][2] + dA[n][3] * tm[m][3];
        sv[m] = s; mx = fmaxf(mx, s);
      }
      float ssum = 0.f;
#pragma unroll
      for (int m = 0; m < 10; m++) { float e = expf(sv[m] - mx); sv[m] = e; ssum += e; }
      float inv = 1.0f / ssum;
#pragma unroll
      for (int m = 0; m < 10; m++) cm[m] += sv[m] * inv;
    }
    float u0 = 0.f, u1 = 0.f, u2 = 0.f, u3 = 0.f;
#pragma unroll
    for (int m = 0; m < 10; m++) {
      u0 += cm[m] * dA[m][0]; u1 += cm[m] * dA[m][1];
      u2 += cm[m] * dA[m][2]; u3 += cm[m] * dA[m][3];
    }
    f32x4 dv;
#pragma unroll
    for (int rp = 0; rp < 4; rp++)
      dv[rp] = u0 * Mv[rp] + u1 * Mv[4 + rp] + u2 * Mv[8 + rp] + u3 * Mv[12 + rp];
    *reinterpret_cast<f32x4*>(&dom[(rows0 + row) << 2]) = dv;
  }
}

// ---------------- mainGEMM: out = relu(x@kernel + bias_tot + dom@Beff), 128x128xBK64 ----------------
__launch_bounds__(256, 2)
__global__ void mainGEMM(const float* __restrict__ x, const unsigned short* __restrict__ kb,
                         const float* __restrict__ ws_f, float* __restrict__ out) {
  __shared__ unsigned short As[2][8192];  // 2 x 128x64 bf16, XOR-swizzled 16B chunks
  __shared__ unsigned short Bs[2][8192];
  const int t = threadIdx.x;
  const int w = t >> 6, l = t & 63;
  const int bn = blockIdx.x & 7, bm = blockIdx.x >> 3;
  const int rows0 = bm << 7, cols0 = bn << 7;
  const int wr = w >> 1, wc = w & 1;
  const int lr = l & 15, kg = l >> 4;
  const float* dom  = ws_f + (WS_DOM >> 2);
  const float* beff = ws_f + (WS_BEFF >> 2);
  const float* btot = ws_f + (WS_BIAS >> 2);
  const f32x4 zero4 = {0.f, 0.f, 0.f, 0.f};
  f32x4 acc[4][4];
#pragma unroll
  for (int i = 0; i < 4; i++)
#pragma unroll
    for (int j = 0; j < 4; j++) acc[i][j] = zero4;

  // prologue: stage kc=0 into buf 0
#pragma unroll
  for (int i = 0; i < 4; i++) {
    int segid = i * 256 + t;
    int c = segid >> 3, ks = segid & 7;
    gload_lds16(kb + (cols0 + c) * 1024 + ((ks ^ (c & 7)) << 3), Bs[0] + segid * 8);
  }
#pragma unroll
  for (int i = 0; i < 4; i++) {
    int segid = i * 256 + t;
    int row = segid >> 3, ks = segid & 7;
    const float* gp = x + (rows0 + row) * 1024 + (ks << 3);
    f32x4 v0 = *reinterpret_cast<const f32x4*>(gp);
    f32x4 v1 = *reinterpret_cast<const f32x4*>(gp + 4);
    u32x4 o = { f2bf2(v0[0], v0[1]), f2bf2(v0[2], v0[3]),
                f2bf2(v1[0], v1[1]), f2bf2(v1[2], v1[3]) };
    *reinterpret_cast<u32x4*>(As[0] + row * 64 + ((ks ^ (row & 7)) << 3)) = o;
  }

#pragma unroll 1
  for (int kc = 0; kc < 16; kc++) {
    const int cur = kc & 1, nxt = cur ^ 1;
    __syncthreads();
    f32x4 va[4][2];
    if (kc < 15) {
      // issue next B tile (async to other buffer) + next A global loads before compute
#pragma unroll
      for (int i = 0; i < 4; i++) {
        int segid = i * 256 + t;
        int c = segid >> 3, ks = segid & 7;
        gload_lds16(kb + (cols0 + c) * 1024 + ((kc + 1) << 6) + ((ks ^ (c & 7)) << 3),
                    Bs[nxt] + segid * 8);
      }
#pragma unroll
      for (int i = 0; i < 4; i++) {
        int segid = i * 256 + t;
        int row = segid >> 3, ks = segid & 7;
        const float* gp = x + (rows0 + row) * 1024 + ((kc + 1) << 6) + (ks << 3);
        va[i][0] = *reinterpret_cast<const f32x4*>(gp);
        va[i][1] = *reinterpret_cast<const f32x4*>(gp + 4);
      }
    }
    // compute current buffer
#pragma unroll
    for (int kh = 0; kh < 2; kh++) {
      const int cp = (kh << 2) + kg;
      s16x8 av[4], bv[4];
#pragma unroll
      for (int mf = 0; mf < 4; mf++) {
        int arow = (wr << 6) + (mf << 4) + lr;
        av[mf] = *reinterpret_cast<const s16x8*>(As[cur] + arow * 64 + ((cp ^ (arow & 7)) << 3));
      }
#pragma unroll
      for (int nf = 0; nf < 4; nf++) {
        int brow = (wc << 6) + (nf << 4) + lr;
        bv[nf] = *reinterpret_cast<const s16x8*>(Bs[cur] + brow * 64 + ((cp ^ (brow & 7)) << 3));
      }
#pragma unroll
      for (int mf = 0; mf < 4; mf++)
#pragma unroll
        for (int nf = 0; nf < 4; nf++)
          acc[mf][nf] = __builtin_amdgcn_mfma_f32_16x16x32_bf16(av[mf], bv[nf], acc[mf][nf], 0, 0, 0);
    }
    if (kc < 15) {
#pragma unroll
      for (int i = 0; i < 4; i++) {
        int segid = i * 256 + t;
        int row = segid >> 3, ks = segid & 7;
        u32x4 o = { f2bf2(va[i][0][0], va[i][0][1]), f2bf2(va[i][0][2], va[i][0][3]),
                    f2bf2(va[i][1][0], va[i][1][1]), f2bf2(va[i][1][2], va[i][1][3]) };
        *reinterpret_cast<u32x4*>(As[nxt] + row * 64 + ((ks ^ (row & 7)) << 3)) = o;
      }
    }
  }

  // epilogue: + bias_tot + dom@Beff, relu
  float bcv[4], bev[4][4];
#pragma unroll
  for (int nf = 0; nf < 4; nf++) {
    int col = cols0 + (wc << 6) + (nf << 4) + lr;
    bcv[nf] = btot[col];
#pragma unroll
    for (int r = 0; r < 4; r++) bev[nf][r] = beff[r * 1024 + col];
  }
#pragma unroll
  for (int mf = 0; mf < 4; mf++) {
    const int rbase = rows0 + (wr << 6) + (mf << 4) + (kg << 2);
    f32x4 dm[4];
#pragma unroll
    for (int j = 0; j < 4; j++)
      dm[j] = *reinterpret_cast<const f32x4*>(dom + ((rbase + j) << 2));
#pragma unroll
    for (int nf = 0; nf < 4; nf++) {
      const int col = cols0 + (wc << 6) + (nf << 4) + lr;
#pragma unroll
      for (int j = 0; j < 4; j++) {
        float v = acc[mf][nf][j] + bcv[nf]
                + dm[j][0] * bev[nf][0] + dm[j][1] * bev[nf][1]
                + dm[j][2] * bev[nf][2] + dm[j][3] * bev[nf][3];
        out[(rbase + j) * 1024 + col] = fmaxf(v, 0.f);
      }
    }
  }
}

extern "C" void kernel_launch(void* const* d_in, const int* in_sizes, int n_in,
                              void* d_out, int out_size, void* d_ws, size_t ws_size,
                              hipStream_t stream) {
  (void)in_sizes; (void)n_in; (void)out_size; (void)ws_size;
  const float* x           = (const float*)d_in[0];
  const int*   dom_ind     = (const int*)d_in[1];
  const float* kern        = (const float*)d_in[2];
  const float* bias        = (const float*)d_in[3];
  const float* a_kernel    = (const float*)d_in[4];
  const float* b_kernel    = (const float*)d_in[5];
  const float* domain_bias = (const float*)d_in[6];
  const float* WQ          = (const float*)d_in[7];
  const float* WK          = (const float*)d_in[8];
  const float* WV          = (const float*)d_in[9];
  const float* linear      = (const float*)d_in[10];
  const float* factor      = (const float*)d_in[11];
  float* out = (float*)d_out;
  char* ws = (char*)d_ws;
  float* ws_f = (float*)ws;
  unsigned short* acatt = (unsigned short*)(ws + WS_ACATT);
  unsigned short* kb    = (unsigned short*)(ws + WS_KB);
  float* dom            = (float*)(ws + WS_DOM);

  prep1<<<1, 256, 0, stream>>>(factor, WQ, WK, WV, linear, bias, domain_bias, b_kernel, dom_ind, ws_f);
  prep2<<<256, 256, 0, stream>>>(a_kernel, acatt);
  transK<<<1024, 256, 0, stream>>>(kern, kb);
  stageA<<<512, 256, 0, stream>>>(x, acatt, ws_f, dom);
  mainGEMM<<<2048, 256, 0, stream>>>(x, kb, ws_f, out);
}

// Round 3
// 146.239 us; speedup vs baseline: 1.5089x; 1.5089x over previous
//
#include <hip/hip_runtime.h>
#include <hip/hip_bf16.h>

// B=32768, D=1024, U=1024, R=4, H=16, ND=11
// out = relu(x@kernel + bias_tot + (dom @ Beff)), dom from tiny collapsed attention.

typedef float f32x4 __attribute__((ext_vector_type(4)));
typedef short s16x8 __attribute__((ext_vector_type(8)));
typedef unsigned int u32x4 __attribute__((ext_vector_type(4)));

// ws layout (bytes)
#define WS_DOM    0u         // 32768*4 f32           = 524288
#define WS_BEFF   524288u    // 4*1024 f32            = 16384
#define WS_BIAS   540672u    // 1024 f32              = 4096
#define WS_G      544768u    // 16 f32
#define WS_M      545024u    // 16 f32
#define WS_ACATT  545280u    // 64*1024 bf16          = 131072
#define WS_KB     679936u    // 1024*1024 bf16        = 2097152 (ends 2777088)
#define WS_XB     2777088u   // 32768*1024 bf16       = 67108864 (ends 69885952)

__device__ __forceinline__ unsigned short f2bf(float f) {
  unsigned int u = __builtin_bit_cast(unsigned int, f);
  u += 0x7fffu + ((u >> 16) & 1u);   // round-to-nearest-even
  return (unsigned short)(u >> 16);
}
__device__ __forceinline__ unsigned int f2bf2(float a, float b) {
  return (unsigned int)f2bf(a) | ((unsigned int)f2bf(b) << 16);
}

__device__ __forceinline__ void gload_lds16(const void* g, void* l) {
  __builtin_amdgcn_global_load_lds((const __attribute__((address_space(1))) void*)g,
                                   (__attribute__((address_space(3))) void*)l, 16, 0, 0);
}

// ---------------- prep1: w, G, M, bias_tot, Beff ----------------
__global__ void prep1(const float* __restrict__ factor, const float* __restrict__ WQ,
                      const float* __restrict__ WK, const float* __restrict__ WV,
                      const float* __restrict__ linear, const float* __restrict__ bias,
                      const float* __restrict__ domain_bias, const float* __restrict__ b_kernel,
                      const int* __restrict__ dom_ind, float* __restrict__ ws_f) {
  __shared__ float wsm[10];
  const int t = threadIdx.x;
  float* G    = ws_f + (WS_G >> 2);
  float* M    = ws_f + (WS_M >> 2);
  float* beff = ws_f + (WS_BEFF >> 2);
  float* btot = ws_f + (WS_BIAS >> 2);
  if (t == 0) {
    float f[11], mx = -1e30f;
    for (int i = 0; i < 11; i++) { f[i] = factor[i]; mx = fmaxf(mx, f[i]); }
    float s = 0.f;
    for (int i = 0; i < 11; i++) { f[i] = expf(f[i] - mx); s += f[i]; }
    float inv = 1.0f / s;
    for (int i = 0; i < 10; i++) wsm[i] = f[i + 1] * inv;
  }
  if (t < 16) {
    int r = t >> 2, c = t & 3;
    float g = 0.f, m = 0.f;
    for (int h = 0; h < 16; h++) {
      g += WQ[r * 16 + h] * WK[c * 16 + h];
      m += WV[r * 16 + h] * linear[h * 4 + c];
    }
    G[t] = 0.25f * g;   // scale = 1/sqrt(H) = 0.25
    M[t] = m;
  }
  __syncthreads();
  const int idx = dom_ind[0];
  for (int u = t; u < 1024; u += 256) btot[u] = bias[u] + domain_bias[idx * 1024 + u];
  for (int i = t; i < 4096; i += 256) {
    int r = i >> 10, u = i & 1023;
    float s = 0.f;
    for (int n = 0; n < 10; n++) s += wsm[n] * b_kernel[(1 + n) * 4096 + r * 1024 + u];
    beff[i] = s;
  }
}

// ---------------- prep2: Acatt[c][d] bf16, c=n*4+r (transposed, zero-padded to 64) ----------------
__global__ void prep2(const float* __restrict__ a_kernel, unsigned short* __restrict__ acatt) {
  const int i = blockIdx.x * 256 + threadIdx.x;  // 65536
  const int c = i >> 10, d = i & 1023;
  float v = 0.0f;
  if (c < 40) v = a_kernel[(1 + (c >> 2)) * 4096 + d * 4 + (c & 3)];
  acatt[i] = f2bf(v);
}

// ---------------- transK: kb[n][k] = bf16(kernel[k][n]) ----------------
__global__ void transK(const float* __restrict__ kern, unsigned short* __restrict__ kb) {
  __shared__ float tile[32][33];
  const int t = threadIdx.x;
  const int kt = blockIdx.x >> 5, nt = blockIdx.x & 31;
  const int k0 = kt << 5, n0 = nt << 5;
  const int row = t >> 5, col = t & 31;
#pragma unroll
  for (int i = 0; i < 4; i++)
    tile[row + i * 8][col] = kern[(k0 + row + i * 8) * 1024 + n0 + col];
  __syncthreads();
  const int nrow = t >> 3, kq = t & 7;
  uint2 pv;
  pv.x = f2bf2(tile[kq * 4 + 0][nrow], tile[kq * 4 + 1][nrow]);
  pv.y = f2bf2(tile[kq * 4 + 2][nrow], tile[kq * 4 + 3][nrow]);
  *reinterpret_cast<uint2*>(&kb[(n0 + nrow) * 1024 + k0 + kq * 4]) = pv;
}

// ---------------- stageA: dA = x@Acat (MFMA) + attention -> dom; optionally writes xb(bf16) ----------------
template <bool WRITEXB>
__launch_bounds__(256, 2)
__global__ void stageA(const float* __restrict__ x, const unsigned short* __restrict__ acatt,
                       const float* __restrict__ ws_f, float* __restrict__ dom,
                       unsigned short* __restrict__ xb) {
  __shared__ unsigned short As[64 * 64];   // [row][chunk^swz][8] bf16
  __shared__ unsigned short Bs[64 * 64];
  __shared__ float dAs[64][45];
  const int t = threadIdx.x;
  const int w = t >> 6, l = t & 63;
  const int rows0 = blockIdx.x << 6;
  const int lr = l & 15, kg = l >> 4;
  const f32x4 zero4 = {0.f, 0.f, 0.f, 0.f};
  f32x4 acc[3]; acc[0] = zero4; acc[1] = zero4; acc[2] = zero4;

#pragma unroll 1
  for (int kc = 0; kc < 16; kc++) {
    if (kc) __syncthreads();
    // B tile: Acatt rows (already bf16) via source-pre-swizzled global_load_lds
#pragma unroll
    for (int i = 0; i < 2; i++) {
      int segid = i * 256 + t;
      int c = segid >> 3, ks = segid & 7;
      gload_lds16(acatt + c * 1024 + (kc << 6) + ((ks ^ (c & 7)) << 3), Bs + segid * 8);
    }
    // A tile: x f32 -> bf16 reg-staged, swizzled ds_write (+ linear global xb write)
#pragma unroll
    for (int i = 0; i < 2; i++) {
      int segid = i * 256 + t;
      int row = segid >> 3, ks = segid & 7;
      const float* gp = x + (rows0 + row) * 1024 + (kc << 6) + (ks << 3);
      f32x4 v0 = *reinterpret_cast<const f32x4*>(gp);
      f32x4 v1 = *reinterpret_cast<const f32x4*>(gp + 4);
      u32x4 o = { f2bf2(v0[0], v0[1]), f2bf2(v0[2], v0[3]),
                  f2bf2(v1[0], v1[1]), f2bf2(v1[2], v1[3]) };
      *reinterpret_cast<u32x4*>(As + row * 64 + ((ks ^ (row & 7)) << 3)) = o;
      if (WRITEXB)
        *reinterpret_cast<u32x4*>(xb + (rows0 + row) * 1024 + (kc << 6) + (ks << 3)) = o;
    }
    __syncthreads();
#pragma unroll
    for (int kh = 0; kh < 2; kh++) {
      const int cp = (kh << 2) + kg;
      const int arow = (w << 4) + lr;
      s16x8 av = *reinterpret_cast<const s16x8*>(As + arow * 64 + ((cp ^ (arow & 7)) << 3));
#pragma unroll
      for (int nf = 0; nf < 3; nf++) {
        int brow = (nf << 4) + lr;
        s16x8 bv = *reinterpret_cast<const s16x8*>(Bs + brow * 64 + ((cp ^ (brow & 7)) << 3));
        acc[nf] = __builtin_amdgcn_mfma_f32_16x16x32_bf16(av, bv, acc[nf], 0, 0, 0);
      }
    }
  }
  __syncthreads();
  // scatter dA (cols 0..39) into LDS; each wave owns its 16 rows fully
#pragma unroll
  for (int nf = 0; nf < 3; nf++) {
    int col = (nf << 4) + lr;
    if (col < 40) {
#pragma unroll
      for (int j = 0; j < 4; j++)
        dAs[(w << 4) + (kg << 2) + j][col] = acc[nf][j];
    }
  }
  __syncthreads();
  if (l < 16) {
    const int row = (w << 4) + l;
    const float* Gp = ws_f + (WS_G >> 2);
    const float* Mp = ws_f + (WS_M >> 2);
    float dA[10][4];
#pragma unroll
    for (int m = 0; m < 10; m++)
#pragma unroll
      for (int r = 0; r < 4; r++) dA[m][r] = dAs[row][(m << 2) + r];
    float Gv[16], Mv[16];
#pragma unroll
    for (int i = 0; i < 16; i++) { Gv[i] = Gp[i]; Mv[i] = Mp[i]; }
    float tm[10][4];
#pragma unroll
    for (int m = 0; m < 10; m++)
#pragma unroll
      for (int r = 0; r < 4; r++)
        tm[m][r] = Gv[(r << 2) + 0] * dA[m][0] + Gv[(r << 2) + 1] * dA[m][1]
                 + Gv[(r << 2) + 2] * dA[m][2] + Gv[(r << 2) + 3] * dA[m][3];
    float cm[10];
#pragma unroll
    for (int m = 0; m < 10; m++) cm[m] = 0.f;
#pragma unroll
    for (int n = 0; n < 10; n++) {
      float sv[10]; float mx = -1e30f;
#pragma unroll
      for (int m = 0; m < 10; m++) {
        float s = dA[n][0] * tm[m][0] + dA[n][1] * tm[m][1]
                + dA[n][2] * tm[m][2] + dA[n][3] * tm[m][3];
        sv[m] = s; mx = fmaxf(mx, s);
      }
      float ssum = 0.f;
#pragma unroll
      for (int m = 0; m < 10; m++) { float e = expf(sv[m] - mx); sv[m] = e; ssum += e; }
      float inv = 1.0f / ssum;
#pragma unroll
      for (int m = 0; m < 10; m++) cm[m] += sv[m] * inv;
    }
    float u0 = 0.f, u1 = 0.f, u2 = 0.f, u3 = 0.f;
#pragma unroll
    for (int m = 0; m < 10; m++) {
      u0 += cm[m] * dA[m][0]; u1 += cm[m] * dA[m][1];
      u2 += cm[m] * dA[m][2]; u3 += cm[m] * dA[m][3];
    }
    f32x4 dv;
#pragma unroll
    for (int rp = 0; rp < 4; rp++)
      dv[rp] = u0 * Mv[rp] + u1 * Mv[4 + rp] + u2 * Mv[8 + rp] + u3 * Mv[12 + rp];
    *reinterpret_cast<f32x4*>(&dom[(rows0 + row) << 2]) = dv;
  }
}

// ---------------- mainGEMM: out = relu(x@kernel + bias_tot + dom@Beff) ----------------
// 128x128xBK64, single-buffered m97 structure (2 barriers/K-step), XCD-locality swizzle.
template <bool XB>
__launch_bounds__(256, 3)
__global__ void mainGEMM(const float* __restrict__ x, const unsigned short* __restrict__ xb,
                         const unsigned short* __restrict__ kb,
                         const float* __restrict__ ws_f, float* __restrict__ out) {
  __shared__ unsigned short As[8192];  // 128x64 bf16, XOR-swizzled 16B chunks
  __shared__ unsigned short Bs[8192];
  const int t = threadIdx.x;
  const int w = t >> 6, l = t & 63;
  // XCD-locality swizzle: xcd = b&7 owns 32 contiguous row-panels, col-tiles inner.
  const int b = blockIdx.x;
  const int xcd = b & 7, i6 = b >> 3;
  const int bm = (xcd << 5) + (i6 >> 3), bn = i6 & 7;
  const int rows0 = bm << 7, cols0 = bn << 7;
  const int wr = w >> 1, wc = w & 1;
  const int lr = l & 15, kg = l >> 4;
  const float* dom  = ws_f + (WS_DOM >> 2);
  const float* beff = ws_f + (WS_BEFF >> 2);
  const float* btot = ws_f + (WS_BIAS >> 2);
  const f32x4 zero4 = {0.f, 0.f, 0.f, 0.f};
  f32x4 acc[4][4];
#pragma unroll
  for (int i = 0; i < 4; i++)
#pragma unroll
    for (int j = 0; j < 4; j++) acc[i][j] = zero4;

#pragma unroll 1
  for (int kc = 0; kc < 16; kc++) {
    if (kc) __syncthreads();
    // stage B tile via source-pre-swizzled global_load_lds
#pragma unroll
    for (int i = 0; i < 4; i++) {
      int segid = i * 256 + t;
      int c = segid >> 3, ks = segid & 7;
      gload_lds16(kb + (cols0 + c) * 1024 + (kc << 6) + ((ks ^ (c & 7)) << 3), Bs + segid * 8);
    }
    // stage A tile
#pragma unroll
    for (int i = 0; i < 4; i++) {
      int segid = i * 256 + t;
      int row = segid >> 3, ks = segid & 7;
      if (XB) {
        gload_lds16(xb + (rows0 + row) * 1024 + (kc << 6) + ((ks ^ (row & 7)) << 3),
                    As + segid * 8);
      } else {
        const float* gp = x + (rows0 + row) * 1024 + (kc << 6) + (ks << 3);
        f32x4 v0 = *reinterpret_cast<const f32x4*>(gp);
        f32x4 v1 = *reinterpret_cast<const f32x4*>(gp + 4);
        u32x4 o = { f2bf2(v0[0], v0[1]), f2bf2(v0[2], v0[3]),
                    f2bf2(v1[0], v1[1]), f2bf2(v1[2], v1[3]) };
        *reinterpret_cast<u32x4*>(As + row * 64 + ((ks ^ (row & 7)) << 3)) = o;
      }
    }
    __syncthreads();
    // compute
#pragma unroll
    for (int kh = 0; kh < 2; kh++) {
      const int cp = (kh << 2) + kg;
      s16x8 av[4], bv[4];
#pragma unroll
      for (int mf = 0; mf < 4; mf++) {
        int arow = (wr << 6) + (mf << 4) + lr;
        av[mf] = *reinterpret_cast<const s16x8*>(As + arow * 64 + ((cp ^ (arow & 7)) << 3));
      }
#pragma unroll
      for (int nf = 0; nf < 4; nf++) {
        int brow = (wc << 6) + (nf << 4) + lr;
        bv[nf] = *reinterpret_cast<const s16x8*>(Bs + brow * 64 + ((cp ^ (brow & 7)) << 3));
      }
#pragma unroll
      for (int mf = 0; mf < 4; mf++)
#pragma unroll
        for (int nf = 0; nf < 4; nf++)
          acc[mf][nf] = __builtin_amdgcn_mfma_f32_16x16x32_bf16(av[mf], bv[nf], acc[mf][nf], 0, 0, 0);
    }
  }

  // epilogue: + bias_tot + dom@Beff, relu
  float bcv[4], bev[4][4];
#pragma unroll
  for (int nf = 0; nf < 4; nf++) {
    int col = cols0 + (wc << 6) + (nf << 4) + lr;
    bcv[nf] = btot[col];
#pragma unroll
    for (int r = 0; r < 4; r++) bev[nf][r] = beff[r * 1024 + col];
  }
#pragma unroll
  for (int mf = 0; mf < 4; mf++) {
    const int rbase = rows0 + (wr << 6) + (mf << 4) + (kg << 2);
    f32x4 dm[4];
#pragma unroll
    for (int j = 0; j < 4; j++)
      dm[j] = *reinterpret_cast<const f32x4*>(dom + ((rbase + j) << 2));
#pragma unroll
    for (int nf = 0; nf < 4; nf++) {
      const int col = cols0 + (wc << 6) + (nf << 4) + lr;
#pragma unroll
      for (int j = 0; j < 4; j++) {
        float v = acc[mf][nf][j] + bcv[nf]
                + dm[j][0] * bev[nf][0] + dm[j][1] * bev[nf][1]
                + dm[j][2] * bev[nf][2] + dm[j][3] * bev[nf][3];
        out[(rbase + j) * 1024 + col] = fmaxf(v, 0.f);
      }
    }
  }
}

extern "C" void kernel_launch(void* const* d_in, const int* in_sizes, int n_in,
                              void* d_out, int out_size, void* d_ws, size_t ws_size,
                              hipStream_t stream) {
  (void)in_sizes; (void)n_in; (void)out_size;
  const float* x           = (const float*)d_in[0];
  const int*   dom_ind     = (const int*)d_in[1];
  const float* kern        = (const float*)d_in[2];
  const float* bias        = (const float*)d_in[3];
  const float* a_kernel    = (const float*)d_in[4];
  const float* b_kernel    = (const float*)d_in[5];
  const float* domain_bias = (const float*)d_in[6];
  const float* WQ          = (const float*)d_in[7];
  const float* WK          = (const float*)d_in[8];
  const float* WV          = (const float*)d_in[9];
  const float* linear      = (const float*)d_in[10];
  const float* factor      = (const float*)d_in[11];
  float* out = (float*)d_out;
  char* ws = (char*)d_ws;
  float* ws_f = (float*)ws;
  unsigned short* acatt = (unsigned short*)(ws + WS_ACATT);
  unsigned short* kb    = (unsigned short*)(ws + WS_KB);
  unsigned short* xb    = (unsigned short*)(ws + WS_XB);
  float* dom            = (float*)(ws + WS_DOM);
  const bool use_xb = ws_size >= (size_t)WS_XB + (size_t)32768 * 1024 * 2;

  prep1<<<1, 256, 0, stream>>>(factor, WQ, WK, WV, linear, bias, domain_bias, b_kernel, dom_ind, ws_f);
  prep2<<<256, 256, 0, stream>>>(a_kernel, acatt);
  transK<<<1024, 256, 0, stream>>>(kern, kb);
  if (use_xb) {
    stageA<true><<<512, 256, 0, stream>>>(x, acatt, ws_f, dom, xb);
    mainGEMM<true><<<2048, 256, 0, stream>>>(x, xb, kb, ws_f, out);
  } else {
    stageA<false><<<512, 256, 0, stream>>>(x, acatt, ws_f, dom, xb);
    mainGEMM<false><<<2048, 256, 0, stream>>>(x, xb, kb, ws_f, out);
  }
}